// Round 6
// baseline (260.383 us; speedup 1.0000x reference)
//
#include <hip/hip_runtime.h>

// Shapes (fixed)
#define SEQ   2048
#define NB    2
#define NHQ   32
#define NHKV  8
#define HD    128
#define QTILE 256      // q rows per block (4 waves x 64 q)
#define QW    64       // q rows per wave (two 32-row q-sets)
#define KVB   64
#define NWAVE 4
#define SCALE 0.08838834764831845f
#define QSCALE (0.08838834764831845f * 1.4426950408889634f)   // fold log2(e): use exp2
#define THRL2 11.5f    // defer-max threshold (~8 nats) in log2 domain

#define QSTRIDE (NB * NHQ * HD)    // 8192
#define KSTRIDE (NB * NHKV * HD)   // 2048

typedef float f32x4  __attribute__((ext_vector_type(4)));
typedef float f32x16 __attribute__((ext_vector_type(16)));
typedef __bf16 bf16x8 __attribute__((ext_vector_type(8)));
typedef unsigned short ushort8 __attribute__((ext_vector_type(8)));
typedef unsigned int u32;
typedef unsigned int u32x2 __attribute__((ext_vector_type(2)));
typedef unsigned int u32x4 __attribute__((ext_vector_type(4)));

__device__ __forceinline__ unsigned short f2bf(float f) {
    union { float f; unsigned u; } c; c.f = f;
    return (unsigned short)((c.u + 0x7fffu + ((c.u >> 16) & 1u)) >> 16);
}

__device__ __forceinline__ void gload_lds16(const unsigned short* g, unsigned short* l) {
    __builtin_amdgcn_global_load_lds((const __attribute__((address_space(1))) u32*)g,
                                     (__attribute__((address_space(3))) u32*)l, 16, 0, 0);
}

__device__ __forceinline__ float ex2(float x) {
#if __has_builtin(__builtin_amdgcn_exp2f)
    return __builtin_amdgcn_exp2f(x);
#else
    return exp2f(x);
#endif
}

__device__ __forceinline__ u32 cvtpk(float lo, float hi) {
    u32 r;
    asm("v_cvt_pk_bf16_f32 %0, %1, %2" : "=v"(r) : "v"(lo), "v"(hi));
    return r;
}

// v_permlane32_swap_b32 a, b : swaps a's UPPER 32 lanes with b's LOWER 32 lanes
__device__ __forceinline__ void pl32swap(u32& a, u32& b) {
#if __has_builtin(__builtin_amdgcn_permlane32_swap)
    u32x2 r = __builtin_amdgcn_permlane32_swap(a, b, false, false);
    a = r.x; b = r.y;
#else
    asm("v_permlane32_swap_b32 %0, %1" : "+v"(a), "+v"(b));
#endif
}

// Pack 8 f32 P values (C-layout rows r=B..B+7) into one PV B-fragment:
// pa elem j = P[8h + j]. Verified R4.
template <int B>
__device__ __forceinline__ bf16x8 make_pa(const f32x16 p) {
    u32 w0 = cvtpk(p[B + 0], p[B + 1]);
    u32 w2 = cvtpk(p[B + 4], p[B + 5]);
    pl32swap(w0, w2);
    u32 w1 = cvtpk(p[B + 2], p[B + 3]);
    u32 w3 = cvtpk(p[B + 6], p[B + 7]);
    pl32swap(w1, w3);
    u32x4 v = {w0, w1, w2, w3};
    return __builtin_bit_cast(bf16x8, v);
}

// ---------------- pre-pass 1: K -> bf16, XOR-swizzled 16B chunks ----------------
__global__ __launch_bounds__(256) void conv_k(const float* __restrict__ K,
                                              unsigned short* __restrict__ Kws) {
    int idx = blockIdx.x * 256 + threadIdx.x;
    int c  = idx & 15;
    int s  = (idx >> 4) & 2047;
    int bh = idx >> 15;
    int cs = c ^ (s & 7);
    const float* src = K + ((size_t)s * 16 + bh) * 128 + cs * 8;
    float4 f0 = *(const float4*)src;
    float4 f1 = *(const float4*)(src + 4);
    ushort8 u;
    u[0] = f2bf(f0.x); u[1] = f2bf(f0.y); u[2] = f2bf(f0.z); u[3] = f2bf(f0.w);
    u[4] = f2bf(f1.x); u[5] = f2bf(f1.y); u[6] = f2bf(f1.z); u[7] = f2bf(f1.w);
    *(ushort8*)&Kws[((size_t)bh * 2048 + s) * 128 + c * 8] = u;
}

// ---------------- pre-pass 2: V -> bf16 transposed [bh][d][seq], swizzled ----------------
__global__ __launch_bounds__(256) void conv_v(const float* __restrict__ V,
                                              unsigned short* __restrict__ Vt) {
    __shared__ float tile[64][129];
    int t64 = blockIdx.x & 31;
    int bh  = blockIdx.x >> 5;
    int kv0 = t64 * 64;
#pragma unroll
    for (int i = 0; i < 8; ++i) {
        int f4 = i * 256 + threadIdx.x;
        int kv = f4 >> 5, d4 = (f4 & 31) * 4;
        float4 v = *(const float4*)(V + ((size_t)(kv0 + kv) * 16 + bh) * 128 + d4);
        tile[kv][d4] = v.x; tile[kv][d4 + 1] = v.y;
        tile[kv][d4 + 2] = v.z; tile[kv][d4 + 3] = v.w;
    }
    __syncthreads();
#pragma unroll
    for (int i = 0; i < 4; ++i) {
        int lin = i * 256 + threadIdx.x;
        int c = lin & 7, d = lin >> 3;
        int cs = c ^ (d & 7);
        ushort8 u;
#pragma unroll
        for (int j = 0; j < 8; ++j) u[j] = f2bf(tile[cs * 8 + j][d]);
        *(ushort8*)&Vt[((size_t)bh * 128 + d) * 2048 + kv0 + c * 8] = u;
    }
}

// -------- main kernel: 4 waves x 64q (2 q-sets), 32x32 MFMA, kv-half split, 2 blocks/CU --------
__global__ __launch_bounds__(256, 2)
void attn_fwd5(const float* __restrict__ Q, const unsigned short* __restrict__ Kws,
               const unsigned short* __restrict__ Vtws, float* __restrict__ O) {
    // [0,16384) kbuf0 | [16384,32768) kbuf1 | [32768,49152) vbuf0 | [49152,65536) vbuf1
    // epilogue reuses [0,34816): 4 waves x 32x68 f32
    __shared__ __align__(16) unsigned char smemc[65536];

    const int tid  = threadIdx.x;
    const int w    = tid >> 6;
    const int lane = tid & 63;
    const int q31  = lane & 31;
    const int h    = lane >> 5;
    const int c7   = q31 & 7;

    // XCD-locality decode: hkv = bid&7 -> all blocks on one XCD share one hkv (KV fits L2)
    const int bid   = blockIdx.x;
    const int hkv   = bid & 7;
    const int rest  = bid >> 3;
    const int g     = rest & 3;
    const int b     = (rest >> 2) & 1;
    const int qtile = rest >> 3;          // 0..7
    const int hq    = hkv * 4 + g;

    const int qbase = qtile * QTILE + w * QW;

    // ---- Q B-fragments for both q-sets: qf[qs][s] elem j = Q[q][16s+8h+j]*QSCALE ----
    bf16x8 qfa[8], qfb[8];
#pragma unroll
    for (int qs = 0; qs < 2; ++qs) {
        const float* qp = Q + (size_t)(qbase + qs * 32 + q31) * QSTRIDE + b * (NHQ * HD) + hq * HD;
#pragma unroll
        for (int s = 0; s < 8; ++s) {
            const float* p = qp + (2 * s + h) * 8;
            float4 f0 = *(const float4*)(p);
            float4 f1 = *(const float4*)(p + 4);
            ushort8 u;
            u[0] = f2bf(f0.x * QSCALE); u[1] = f2bf(f0.y * QSCALE);
            u[2] = f2bf(f0.z * QSCALE); u[3] = f2bf(f0.w * QSCALE);
            u[4] = f2bf(f1.x * QSCALE); u[5] = f2bf(f1.y * QSCALE);
            u[6] = f2bf(f1.z * QSCALE); u[7] = f2bf(f1.w * QSCALE);
            if (qs == 0) qfa[s] = __builtin_bit_cast(bf16x8, u);
            else         qfb[s] = __builtin_bit_cast(bf16x8, u);
        }
    }

    // per-lane LDS byte addresses (buffer 0), XOR-toggled per tile
    u32 kad[8], vad[4];
#pragma unroll
    for (int s = 0; s < 8; ++s)
        kad[s] = q31 * 256 + (((2 * s + h) ^ c7) << 4);
#pragma unroll
    for (int ks = 0; ks < 4; ++ks)
        vad[ks] = 32768 + q31 * 128 + (((2 * ks + h) ^ c7) << 4);

    f32x16 acca[4], accb[4];
#pragma unroll
    for (int db = 0; db < 4; ++db) { acca[db] = (f32x16)0.f; accb[db] = (f32x16)0.f; }
    float mra = -3e38f, lsa = 0.f, mrb = -3e38f, lsb = 0.f;

    const unsigned short* kbh = Kws  + (size_t)(b * 8 + hkv) * 2048 * 128;
    const unsigned short* vbh = Vtws + (size_t)(b * 8 + hkv) * 128 * 2048;

    // 4 waves stage 16 KB K + 16 KB V per tile: 4 K-chunks + 4 V-chunks (1 KB) per wave
#define STAGE(bufi, tt) do {                                                           \
        const int kv0s = (tt) * KVB;                                                   \
        _Pragma("unroll")                                                              \
        for (int i_ = 0; i_ < 4; ++i_) {                                               \
            const int c_ = w * 4 + i_;                                                 \
            gload_lds16(kbh + (size_t)(kv0s + c_ * 4 + (lane >> 4)) * 128 + (lane & 15) * 8, \
                        (unsigned short*)(smemc + (bufi) * 16384 + c_ * 1024));        \
            gload_lds16(vbh + (size_t)(c_ * 8 + (lane >> 3)) * 2048 + kv0s + (lane & 7) * 8, \
                        (unsigned short*)(smemc + 32768 + (bufi) * 16384 + c_ * 1024)); \
        }                                                                              \
    } while (0)

    STAGE(0, 0);

    for (int t = 0; t < SEQ / KVB; ++t) {
        __syncthreads();
        if (t + 1 < SEQ / KVB) STAGE((t + 1) & 1, t + 1);

        // two kv-halves of 32 rows each (keeps live S-regs at 32)
#pragma unroll
        for (int X = 0; X < 2; ++X) {
            // ---- S^T half = K_half * Q (K fragment shared by both q-sets) ----
            f32x16 saa = (f32x16)0.f, sab = (f32x16)0.f;
            __builtin_amdgcn_s_setprio(1);
#pragma unroll
            for (int s = 0; s < 8; ++s) {
                bf16x8 kf = *(const bf16x8*)&smemc[kad[s] + X * 8192];
                saa = __builtin_amdgcn_mfma_f32_32x32x16_bf16(kf, qfa[s], saa, 0, 0, 0);
                sab = __builtin_amdgcn_mfma_f32_32x32x16_bf16(kf, qfb[s], sab, 0, 0, 0);
            }
            __builtin_amdgcn_s_setprio(0);

            // ---- online softmax (log2 domain), q-set a ----
            {
                float t0 = fmaxf(fmaxf(saa[0], saa[1]),  fmaxf(saa[2], saa[3]));
                float t1 = fmaxf(fmaxf(saa[4], saa[5]),  fmaxf(saa[6], saa[7]));
                float t2 = fmaxf(fmaxf(saa[8], saa[9]),  fmaxf(saa[10], saa[11]));
                float t3 = fmaxf(fmaxf(saa[12], saa[13]), fmaxf(saa[14], saa[15]));
                float tm = fmaxf(fmaxf(t0, t1), fmaxf(t2, t3));
                tm = fmaxf(tm, __shfl_xor(tm, 32));
                if (!__all(tm <= mra + THRL2)) {
                    float mn = fmaxf(mra, tm);
                    float corr = ex2(mra - mn);
                    lsa *= corr;
#pragma unroll
                    for (int db = 0; db < 4; ++db)
#pragma unroll
                        for (int r = 0; r < 16; ++r) acca[db][r] *= corr;
                    mra = mn;
                }
#pragma unroll
                for (int r = 0; r < 16; ++r) saa[r] = ex2(saa[r] - mra);
                float s0 = (saa[0] + saa[1]) + (saa[2] + saa[3]);
                float s1 = (saa[4] + saa[5]) + (saa[6] + saa[7]);
                float s2 = (saa[8] + saa[9]) + (saa[10] + saa[11]);
                float s3 = (saa[12] + saa[13]) + (saa[14] + saa[15]);
                lsa += (s0 + s1) + (s2 + s3);      // cross-h shfl deferred to epilogue
            }
            // ---- q-set b ----
            {
                float t0 = fmaxf(fmaxf(sab[0], sab[1]),  fmaxf(sab[2], sab[3]));
                float t1 = fmaxf(fmaxf(sab[4], sab[5]),  fmaxf(sab[6], sab[7]));
                float t2 = fmaxf(fmaxf(sab[8], sab[9]),  fmaxf(sab[10], sab[11]));
                float t3 = fmaxf(fmaxf(sab[12], sab[13]), fmaxf(sab[14], sab[15]));
                float tm = fmaxf(fmaxf(t0, t1), fmaxf(t2, t3));
                tm = fmaxf(tm, __shfl_xor(tm, 32));
                if (!__all(tm <= mrb + THRL2)) {
                    float mn = fmaxf(mrb, tm);
                    float corr = ex2(mrb - mn);
                    lsb *= corr;
#pragma unroll
                    for (int db = 0; db < 4; ++db)
#pragma unroll
                        for (int r = 0; r < 16; ++r) accb[db][r] *= corr;
                    mrb = mn;
                }
#pragma unroll
                for (int r = 0; r < 16; ++r) sab[r] = ex2(sab[r] - mrb);
                float s0 = (sab[0] + sab[1]) + (sab[2] + sab[3]);
                float s1 = (sab[4] + sab[5]) + (sab[6] + sab[7]);
                float s2 = (sab[8] + sab[9]) + (sab[10] + sab[11]);
                float s3 = (sab[12] + sab[13]) + (sab[14] + sab[15]);
                lsb += (s0 + s1) + (s2 + s3);
            }

            // ---- P -> bf16 fragments ----
            bf16x8 paa[2], pab[2];
            paa[0] = make_pa<0>(saa); paa[1] = make_pa<8>(saa);
            pab[0] = make_pa<0>(sab); pab[1] = make_pa<8>(sab);

            // ---- O^T += V^T_half * P^T_half (V fragment shared by both q-sets) ----
            __builtin_amdgcn_s_setprio(1);
#pragma unroll
            for (int db = 0; db < 4; ++db) {
#pragma unroll
                for (int ks = 0; ks < 2; ++ks) {
                    bf16x8 vf = *(const bf16x8*)&smemc[vad[2 * X + ks] + db * 4096];
                    acca[db] = __builtin_amdgcn_mfma_f32_32x32x16_bf16(vf, paa[ks], acca[db], 0, 0, 0);
                    accb[db] = __builtin_amdgcn_mfma_f32_32x32x16_bf16(vf, pab[ks], accb[db], 0, 0, 0);
                }
            }
            __builtin_amdgcn_s_setprio(0);
        }

#pragma unroll
        for (int s = 0; s < 8; ++s) kad[s] ^= 16384;
#pragma unroll
        for (int ks = 0; ks < 4; ++ks) vad[ks] ^= 16384;
    }
#undef STAGE

    // ---- epilogue: final lsum reduce, normalize, LDS transpose, coalesced stores ----
    __syncthreads();   // all waves done reading K/V LDS
    lsa += __shfl_xor(lsa, 32);
    lsb += __shfl_xor(lsb, 32);
    float invla = 1.f / lsa, invlb = 1.f / lsb;
    float* ep = (float*)(void*)smemc + w * 2176;   // 32 x 68 f32 per wave
    float* ob = O + b * (NHQ * HD) + hq * HD;

#pragma unroll
    for (int qs = 0; qs < 2; ++qs) {
        const int qtb = qbase + qs * 32;
        const float invl = qs ? invlb : invla;
#pragma unroll
        for (int pass = 0; pass < 2; ++pass) {
#pragma unroll
            for (int db2 = 0; db2 < 2; ++db2) {
                const int db = pass * 2 + db2;
#pragma unroll
                for (int r = 0; r < 16; ++r) {
                    float v = (qs ? accb[db][r] : acca[db][r]) * invl;
                    ep[q31 * 68 + db2 * 32 + (r & 3) + 8 * (r >> 2) + 4 * h] = v;
                }
            }
            __syncthreads();
#pragma unroll
            for (int i = 0; i < 8; ++i) {
                const int row = i * 4 + (lane >> 4);
                const int f4  = lane & 15;
                float4 val = *(const float4*)&ep[row * 68 + f4 * 4];
                *(float4*)(ob + (size_t)(qtb + row) * QSTRIDE + pass * 64 + f4 * 4) = val;
            }
            __syncthreads();
        }
    }
}

// ---------------- fallback (round-1 kernel, used if ws too small) ----------------
#define KPAD  136
#define VPAD  72
#define PPAD  72
__global__ __launch_bounds__(512, 2)
void attn_fwd(const float* __restrict__ Q, const float* __restrict__ K,
              const float* __restrict__ V, float* __restrict__ O) {
    __shared__ __align__(16) unsigned short kbuf[KVB * KPAD];
    __shared__ __align__(16) unsigned short vbuf[HD * VPAD];
    __shared__ __align__(16) unsigned short pbuf[8][16 * PPAD];

    const int tid = threadIdx.x;
    const int w = tid >> 6, lane = tid & 63;
    const int row16 = lane & 15, kg = lane >> 4;
    const int bid = blockIdx.x;
    const int qtile = bid & 7, g = (bid >> 3) & 3, b = (bid >> 5) & 1, hkv = bid >> 6;
    const int hq = hkv * 4 + g;
    const int qbase = qtile * 256 + w * 32;

    ushort8 qf[2][4];
#pragma unroll
    for (int s = 0; s < 2; ++s) {
        const int qrow = qbase + s * 16 + row16;
        const float* qp = Q + (size_t)qrow * QSTRIDE + b * (NHQ * HD) + hq * HD;
#pragma unroll
        for (int kk = 0; kk < 4; ++kk) {
            const float* p = qp + kk * 32 + kg * 8;
            float4 f0 = *(const float4*)(p);
            float4 f1 = *(const float4*)(p + 4);
            ushort8 u;
            u[0] = f2bf(f0.x * SCALE); u[1] = f2bf(f0.y * SCALE);
            u[2] = f2bf(f0.z * SCALE); u[3] = f2bf(f0.w * SCALE);
            u[4] = f2bf(f1.x * SCALE); u[5] = f2bf(f1.y * SCALE);
            u[6] = f2bf(f1.z * SCALE); u[7] = f2bf(f1.w * SCALE);
            qf[s][kk] = u;
        }
    }
    float m[2][4], lsum[2][4];
    f32x4 acco[2][8];
#pragma unroll
    for (int s = 0; s < 2; ++s)
#pragma unroll
        for (int r = 0; r < 4; ++r) { m[s][r] = -1e30f; lsum[s][r] = 0.f; }
#pragma unroll
    for (int s = 0; s < 2; ++s)
#pragma unroll
        for (int n = 0; n < 8; ++n) acco[s][n] = (f32x4)0.f;

    const float* kb0 = K + b * (NHKV * HD) + hkv * HD;
    const float* vb0 = V + b * (NHKV * HD) + hkv * HD;

    for (int kvt = 0; kvt < SEQ / KVB; ++kvt) {
        const int kv0 = kvt * KVB;
        __syncthreads();
        const float* kb = kb0 + (size_t)kv0 * KSTRIDE;
#pragma unroll
        for (int i = 0; i < 2; ++i) {
            int c = i * 512 + tid;
            int row = c >> 4, c8 = c & 15;
            const float* src = kb + (size_t)row * KSTRIDE + c8 * 8;
            float4 f0 = *(const float4*)(src);
            float4 f1 = *(const float4*)(src + 4);
            ushort8 u;
            u[0] = f2bf(f0.x); u[1] = f2bf(f0.y); u[2] = f2bf(f0.z); u[3] = f2bf(f0.w);
            u[4] = f2bf(f1.x); u[5] = f2bf(f1.y); u[6] = f2bf(f1.z); u[7] = f2bf(f1.w);
            *(ushort8*)&kbuf[row * KPAD + c8 * 8] = u;
        }
        const float* vb = vb0 + (size_t)kv0 * KSTRIDE;
#pragma unroll
        for (int i = 0; i < 4; ++i) {
            int f4i = i * 512 + tid;
            int kv = f4i >> 5, d0 = (f4i & 31) * 4;
            float4 v4 = *(const float4*)(vb + (size_t)kv * KSTRIDE + d0);
            vbuf[(d0 + 0) * VPAD + kv] = f2bf(v4.x);
            vbuf[(d0 + 1) * VPAD + kv] = f2bf(v4.y);
            vbuf[(d0 + 2) * VPAD + kv] = f2bf(v4.z);
            vbuf[(d0 + 3) * VPAD + kv] = f2bf(v4.w);
        }
        __syncthreads();

        f32x4 sa[2][4];
#pragma unroll
        for (int s = 0; s < 2; ++s)
#pragma unroll
            for (int n = 0; n < 4; ++n) sa[s][n] = (f32x4)0.f;
#pragma unroll
        for (int kk = 0; kk < 4; ++kk) {
#pragma unroll
            for (int n = 0; n < 4; ++n) {
                bf16x8 bfr = *(const bf16x8*)&kbuf[(n * 16 + row16) * KPAD + kk * 32 + kg * 8];
                sa[0][n] = __builtin_amdgcn_mfma_f32_16x16x32_bf16(
                    __builtin_bit_cast(bf16x8, qf[0][kk]), bfr, sa[0][n], 0, 0, 0);
                sa[1][n] = __builtin_amdgcn_mfma_f32_16x16x32_bf16(
                    __builtin_bit_cast(bf16x8, qf[1][kk]), bfr, sa[1][n], 0, 0, 0);
            }
        }
#pragma unroll
        for (int s = 0; s < 2; ++s) {
#pragma unroll
            for (int r = 0; r < 4; ++r) {
                float tm = fmaxf(fmaxf(sa[s][0][r], sa[s][1][r]), fmaxf(sa[s][2][r], sa[s][3][r]));
                tm = fmaxf(tm, __shfl_xor(tm, 1, 16));
                tm = fmaxf(tm, __shfl_xor(tm, 2, 16));
                tm = fmaxf(tm, __shfl_xor(tm, 4, 16));
                tm = fmaxf(tm, __shfl_xor(tm, 8, 16));
                float mn = fmaxf(m[s][r], tm);
                float corr = __expf(m[s][r] - mn);
                float ps = 0.f;
                int prow = kg * 4 + r;
#pragma unroll
                for (int n = 0; n < 4; ++n) {
                    float p = __expf(sa[s][n][r] - mn);
                    ps += p;
                    pbuf[w][prow * PPAD + n * 16 + row16] = f2bf(p);
                }
                ps += __shfl_xor(ps, 1, 16);
                ps += __shfl_xor(ps, 2, 16);
                ps += __shfl_xor(ps, 4, 16);
                ps += __shfl_xor(ps, 8, 16);
                lsum[s][r] = lsum[s][r] * corr + ps;
                m[s][r] = mn;
#pragma unroll
                for (int n8 = 0; n8 < 8; ++n8) acco[s][n8][r] *= corr;
            }
#pragma unroll
            for (int kk2 = 0; kk2 < 2; ++kk2) {
                bf16x8 pa = *(const bf16x8*)&pbuf[w][row16 * PPAD + kk2 * 32 + kg * 8];
#pragma unroll
                for (int n8 = 0; n8 < 8; ++n8) {
                    bf16x8 vf = *(const bf16x8*)&vbuf[(n8 * 16 + row16) * VPAD + kk2 * 32 + kg * 8];
                    acco[s][n8] = __builtin_amdgcn_mfma_f32_16x16x32_bf16(pa, vf, acco[s][n8], 0, 0, 0);
                }
            }
        }
    }
    float* ob = O + b * (NHQ * HD) + hq * HD;
#pragma unroll
    for (int s = 0; s < 2; ++s)
#pragma unroll
        for (int r = 0; r < 4; ++r) {
            float inv = 1.f / lsum[s][r];
            int qrow = qbase + s * 16 + kg * 4 + r;
            float* op = ob + (size_t)qrow * QSTRIDE;
#pragma unroll
            for (int n8 = 0; n8 < 8; ++n8)
                op[n8 * 16 + row16] = acco[s][n8][r] * inv;
        }
}

extern "C" void kernel_launch(void* const* d_in, const int* in_sizes, int n_in,
                              void* d_out, int out_size, void* d_ws, size_t ws_size,
                              hipStream_t stream) {
    (void)in_sizes; (void)n_in; (void)out_size;
    const float* Q = (const float*)d_in[0];
    const float* K = (const float*)d_in[1];
    const float* V = (const float*)d_in[2];
    float* Out = (float*)d_out;

    const size_t kv_elems = (size_t)16 * 2048 * 128;
    const size_t need = kv_elems * 2 * sizeof(unsigned short);

    if (ws_size >= need) {
        unsigned short* Kws = (unsigned short*)d_ws;
        unsigned short* Vt  = Kws + kv_elems;
        conv_k<<<dim3(2048), dim3(256), 0, stream>>>(K, Kws);
        conv_v<<<dim3(512), dim3(256), 0, stream>>>(V, Vt);
        attn_fwd5<<<dim3(512), dim3(256), 0, stream>>>(Q, Kws, Vt, Out);
    } else {
        attn_fwd<<<dim3(512), dim3(512), 0, stream>>>(Q, K, V, Out);
    }
}

// Round 7
// 174.313 us; speedup vs baseline: 1.4938x; 1.4938x over previous
//
#include <hip/hip_runtime.h>

// Shapes (fixed)
#define SEQ   2048
#define NB    2
#define NHQ   32
#define NHKV  8
#define HD    128
#define QTILE 256
#define QW    32
#define KVB   64
#define NT    (SEQ / KVB)    // 32 kv tiles
#define SCALE 0.08838834764831845f
#define QSCALE (0.08838834764831845f * 1.4426950408889634f)   // fold log2(e): use exp2
#define THRL2 11.5f

#define QSTRIDE (NB * NHQ * HD)    // 8192
#define KSTRIDE (NB * NHKV * HD)   // 2048

typedef float f32x4  __attribute__((ext_vector_type(4)));
typedef float f32x16 __attribute__((ext_vector_type(16)));
typedef __bf16 bf16x8 __attribute__((ext_vector_type(8)));
typedef unsigned short ushort8 __attribute__((ext_vector_type(8)));
typedef unsigned int u32;
typedef unsigned int u32x2 __attribute__((ext_vector_type(2)));
typedef unsigned int u32x4 __attribute__((ext_vector_type(4)));

__device__ __forceinline__ unsigned short f2bf(float f) {
    union { float f; unsigned u; } c; c.f = f;
    return (unsigned short)((c.u + 0x7fffu + ((c.u >> 16) & 1u)) >> 16);
}

__device__ __forceinline__ void gload_lds16(const unsigned short* g, unsigned short* l) {
    __builtin_amdgcn_global_load_lds((const __attribute__((address_space(1))) u32*)g,
                                     (__attribute__((address_space(3))) u32*)l, 16, 0, 0);
}

__device__ __forceinline__ float ex2(float x) {
#if __has_builtin(__builtin_amdgcn_exp2f)
    return __builtin_amdgcn_exp2f(x);
#else
    return exp2f(x);
#endif
}

__device__ __forceinline__ u32 cvtpk(float lo, float hi) {
    u32 r;
    asm("v_cvt_pk_bf16_f32 %0, %1, %2" : "=v"(r) : "v"(lo), "v"(hi));
    return r;
}

// v_permlane32_swap_b32 a, b : swaps a's UPPER 32 lanes with b's LOWER 32 lanes
__device__ __forceinline__ void pl32swap(u32& a, u32& b) {
#if __has_builtin(__builtin_amdgcn_permlane32_swap)
    u32x2 r = __builtin_amdgcn_permlane32_swap(a, b, false, false);
    a = r.x; b = r.y;
#else
    asm("v_permlane32_swap_b32 %0, %1" : "+v"(a), "+v"(b));
#endif
}

// Pack 8 f32 P values (C-layout rows r=B..B+7) into one PV B-fragment:
// pa elem j = P[8h + j]. Verified R4.
template <int B>
__device__ __forceinline__ bf16x8 make_pa(const f32x16 p) {
    u32 w0 = cvtpk(p[B + 0], p[B + 1]);
    u32 w2 = cvtpk(p[B + 4], p[B + 5]);
    pl32swap(w0, w2);
    u32 w1 = cvtpk(p[B + 2], p[B + 3]);
    u32 w3 = cvtpk(p[B + 6], p[B + 7]);
    pl32swap(w1, w3);
    u32x4 v = {w0, w1, w2, w3};
    return __builtin_bit_cast(bf16x8, v);
}

// ---------------- pre-pass 1: K -> bf16, XOR-swizzled 16B chunks ----------------
__global__ __launch_bounds__(256) void conv_k(const float* __restrict__ K,
                                              unsigned short* __restrict__ Kws) {
    int idx = blockIdx.x * 256 + threadIdx.x;
    int c  = idx & 15;
    int s  = (idx >> 4) & 2047;
    int bh = idx >> 15;
    int cs = c ^ (s & 7);
    const float* src = K + ((size_t)s * 16 + bh) * 128 + cs * 8;
    float4 f0 = *(const float4*)src;
    float4 f1 = *(const float4*)(src + 4);
    ushort8 u;
    u[0] = f2bf(f0.x); u[1] = f2bf(f0.y); u[2] = f2bf(f0.z); u[3] = f2bf(f0.w);
    u[4] = f2bf(f1.x); u[5] = f2bf(f1.y); u[6] = f2bf(f1.z); u[7] = f2bf(f1.w);
    *(ushort8*)&Kws[((size_t)bh * 2048 + s) * 128 + c * 8] = u;
}

// ---------------- pre-pass 2: V -> bf16 transposed [bh][d][seq], swizzled ----------------
__global__ __launch_bounds__(256) void conv_v(const float* __restrict__ V,
                                              unsigned short* __restrict__ Vt) {
    __shared__ float tile[64][129];
    int t64 = blockIdx.x & 31;
    int bh  = blockIdx.x >> 5;
    int kv0 = t64 * 64;
#pragma unroll
    for (int i = 0; i < 8; ++i) {
        int f4 = i * 256 + threadIdx.x;
        int kv = f4 >> 5, d4 = (f4 & 31) * 4;
        float4 v = *(const float4*)(V + ((size_t)(kv0 + kv) * 16 + bh) * 128 + d4);
        tile[kv][d4] = v.x; tile[kv][d4 + 1] = v.y;
        tile[kv][d4 + 2] = v.z; tile[kv][d4 + 3] = v.w;
    }
    __syncthreads();
#pragma unroll
    for (int i = 0; i < 4; ++i) {
        int lin = i * 256 + threadIdx.x;
        int c = lin & 7, d = lin >> 3;
        int cs = c ^ (d & 7);
        ushort8 u;
#pragma unroll
        for (int j = 0; j < 8; ++j) u[j] = f2bf(tile[cs * 8 + j][d]);
        *(ushort8*)&Vt[((size_t)bh * 128 + d) * 2048 + kv0 + c * 8] = u;
    }
}

// -------- main kernel: R4 structure + 3-buffer depth-2 prefetch, counted vmcnt --------
// K region: [0, 49152) = 3 x 16 KB ; V region: [49152, 98304) = 3 x 16 KB
// epilogue reuses [0, 69632): 8 waves x 32x68 f32
__global__ __launch_bounds__(512, 1)
void attn_fwd6(const float* __restrict__ Q, const unsigned short* __restrict__ Kws,
               const unsigned short* __restrict__ Vtws, float* __restrict__ O) {
    __shared__ __align__(16) unsigned char smemc[98304];

    const int tid  = threadIdx.x;
    const int w    = tid >> 6;
    const int lane = tid & 63;
    const int q31  = lane & 31;
    const int h    = lane >> 5;
    const int c7   = q31 & 7;

    // XCD-locality decode: hkv = bid&7
    const int bid   = blockIdx.x;
    const int hkv   = bid & 7;
    const int rest  = bid >> 3;
    const int g     = rest & 3;
    const int b     = (rest >> 2) & 1;
    const int qtile = rest >> 3;          // 0..7
    const int hq    = hkv * 4 + g;

    const int qrow = qtile * QTILE + w * QW + q31;

    // ---- Q B-fragments: qf[s] elem j = Q[qrow][16s+8h+j] * QSCALE ----
    bf16x8 qf[8];
    {
        const float* qp = Q + (size_t)qrow * QSTRIDE + b * (NHQ * HD) + hq * HD;
#pragma unroll
        for (int s = 0; s < 8; ++s) {
            const float* p = qp + (2 * s + h) * 8;
            float4 f0 = *(const float4*)(p);
            float4 f1 = *(const float4*)(p + 4);
            ushort8 u;
            u[0] = f2bf(f0.x * QSCALE); u[1] = f2bf(f0.y * QSCALE);
            u[2] = f2bf(f0.z * QSCALE); u[3] = f2bf(f0.w * QSCALE);
            u[4] = f2bf(f1.x * QSCALE); u[5] = f2bf(f1.y * QSCALE);
            u[6] = f2bf(f1.z * QSCALE); u[7] = f2bf(f1.w * QSCALE);
            qf[s] = __builtin_bit_cast(bf16x8, u);
        }
    }

    // per-lane LDS byte addresses (buffer-0-relative; add kof per tile)
    u32 kad[8], vad[4];
#pragma unroll
    for (int s = 0; s < 8; ++s)
        kad[s] = q31 * 256 + (((2 * s + h) ^ c7) << 4);
#pragma unroll
    for (int ks = 0; ks < 4; ++ks)
        vad[ks] = 49152 + q31 * 128 + (((2 * ks + h) ^ c7) << 4);

    f32x16 acc[4];
#pragma unroll
    for (int db = 0; db < 4; ++db) acc[db] = (f32x16)0.f;
    float mr = -3e38f, lsum = 0.f;

    const unsigned short* kbh = Kws  + (size_t)(b * 8 + hkv) * 2048 * 128;
    const unsigned short* vbh = Vtws + (size_t)(b * 8 + hkv) * 128 * 2048;

    // each wave: 2 K-chunk + 2 V-chunk gload_lds (4 vmem insts) per STAGE
#define STAGE(sofb, tt) do {                                                           \
        const int kv0s = (tt) * KVB;                                                   \
        _Pragma("unroll")                                                              \
        for (int i_ = 0; i_ < 2; ++i_) {                                               \
            const int c_ = w * 2 + i_;                                                 \
            gload_lds16(kbh + (size_t)(kv0s + c_ * 4 + (lane >> 4)) * 128 + (lane & 15) * 8, \
                        (unsigned short*)(smemc + (sofb) + c_ * 1024));                \
            gload_lds16(vbh + (size_t)(c_ * 8 + (lane >> 3)) * 2048 + kv0s + (lane & 7) * 8, \
                        (unsigned short*)(smemc + 49152 + (sofb) + c_ * 1024));        \
        }                                                                              \
    } while (0)

    STAGE(0, 0);
    STAGE(16384, 1);
    int kof = 0;        // compute-buffer byte offset: 0, 16384, 32768, 0, ...
    int sof = 32768;    // stage-target offset (tile t+2)

    for (int t = 0; t < NT; ++t) {
        // tile t's 4 loads were issued 2 tiles ago; allow tile t+1's 4 to stay in flight
        if (t < NT - 1) {
            asm volatile("s_waitcnt vmcnt(4)" ::: "memory");
        } else {
            asm volatile("s_waitcnt vmcnt(0)" ::: "memory");
        }
        __builtin_amdgcn_s_barrier();
        if (t + 2 < NT) STAGE(sof, t + 2);

        // ---- S^T = K * Q : sa0 = kv[0..31], sa1 = kv[32..63] ----
        f32x16 sa0 = (f32x16)0.f, sa1 = (f32x16)0.f;
        __builtin_amdgcn_s_setprio(1);
#pragma unroll
        for (int s = 0; s < 8; ++s) {
            bf16x8 k0 = *(const bf16x8*)&smemc[kad[s] + kof];
            bf16x8 k1 = *(const bf16x8*)&smemc[kad[s] + kof + 8192];
            sa0 = __builtin_amdgcn_mfma_f32_32x32x16_bf16(k0, qf[s], sa0, 0, 0, 0);
            sa1 = __builtin_amdgcn_mfma_f32_32x32x16_bf16(k1, qf[s], sa1, 0, 0, 0);
        }
        __builtin_amdgcn_s_setprio(0);

        // ---- in-register online softmax (log2 domain) ----
        float m4[4];
#pragma unroll
        for (int r = 0; r < 4; ++r)
            m4[r] = fmaxf(fmaxf(fmaxf(sa0[r], sa0[r + 4]), fmaxf(sa0[r + 8], sa0[r + 12])),
                          fmaxf(fmaxf(sa1[r], sa1[r + 4]), fmaxf(sa1[r + 8], sa1[r + 12])));
        float tm = fmaxf(fmaxf(m4[0], m4[1]), fmaxf(m4[2], m4[3]));
        tm = fmaxf(tm, __shfl_xor(tm, 32));

        if (!__all(tm <= mr + THRL2)) {           // defer-max (T13)
            float mn   = fmaxf(mr, tm);
            float corr = ex2(mr - mn);
            lsum *= corr;
#pragma unroll
            for (int db = 0; db < 4; ++db)
#pragma unroll
                for (int r = 0; r < 16; ++r) acc[db][r] *= corr;
            mr = mn;
        }

#pragma unroll
        for (int r = 0; r < 16; ++r) sa0[r] = ex2(sa0[r] - mr);
#pragma unroll
        for (int r = 0; r < 16; ++r) sa1[r] = ex2(sa1[r] - mr);
        float s4[4];
#pragma unroll
        for (int r = 0; r < 4; ++r)
            s4[r] = (sa0[r] + sa0[r + 4]) + (sa0[r + 8] + sa0[r + 12]) +
                    (sa1[r] + sa1[r + 4]) + (sa1[r + 8] + sa1[r + 12]);
        float ps = (s4[0] + s4[1]) + (s4[2] + s4[3]);
        ps += __shfl_xor(ps, 32);
        lsum += ps;

        // ---- P -> bf16 PV fragments ----
        bf16x8 pa[4];
        pa[0] = make_pa<0>(sa0);
        pa[1] = make_pa<8>(sa0);
        pa[2] = make_pa<0>(sa1);
        pa[3] = make_pa<8>(sa1);

        // ---- O^T += V^T * P^T ----
        __builtin_amdgcn_s_setprio(1);
#pragma unroll
        for (int db = 0; db < 4; ++db) {
#pragma unroll
            for (int ks = 0; ks < 4; ++ks) {
                bf16x8 vf = *(const bf16x8*)&smemc[vad[ks] + kof + db * 4096];
                acc[db] = __builtin_amdgcn_mfma_f32_32x32x16_bf16(vf, pa[ks], acc[db], 0, 0, 0);
            }
        }
        __builtin_amdgcn_s_setprio(0);

        kof = (kof == 32768) ? 0 : kof + 16384;
        sof = (sof == 32768) ? 0 : sof + 16384;
    }
#undef STAGE

    // ---- epilogue: normalize in-lane, transpose via LDS, coalesced float4 stores ----
    __syncthreads();   // everyone done reading K/V LDS
    float invl = 1.f / lsum;
    float* ep = (float*)(void*)smemc + w * 2176;   // 32 x 68 f32 per wave
    const int qtb = qtile * QTILE + w * QW;
    float* ob = O + b * (NHQ * HD) + hq * HD;

#pragma unroll
    for (int pass = 0; pass < 2; ++pass) {
#pragma unroll
        for (int db2 = 0; db2 < 2; ++db2) {
            const int db = pass * 2 + db2;
#pragma unroll
            for (int r = 0; r < 16; ++r)
                ep[q31 * 68 + db2 * 32 + (r & 3) + 8 * (r >> 2) + 4 * h] = acc[db][r] * invl;
        }
        __syncthreads();
#pragma unroll
        for (int i = 0; i < 8; ++i) {
            const int row = i * 4 + (lane >> 4);
            const int f4  = lane & 15;
            float4 val = *(const float4*)&ep[row * 68 + f4 * 4];
            *(float4*)(ob + (size_t)(qtb + row) * QSTRIDE + pass * 64 + f4 * 4) = val;
        }
        __syncthreads();
    }
}

// ---------------- fallback (round-1 kernel, used if ws too small) ----------------
#define KPAD  136
#define VPAD  72
#define PPAD  72
__global__ __launch_bounds__(512, 2)
void attn_fwd(const float* __restrict__ Q, const float* __restrict__ K,
              const float* __restrict__ V, float* __restrict__ O) {
    __shared__ __align__(16) unsigned short kbuf[KVB * KPAD];
    __shared__ __align__(16) unsigned short vbuf[HD * VPAD];
    __shared__ __align__(16) unsigned short pbuf[8][16 * PPAD];

    const int tid = threadIdx.x;
    const int w = tid >> 6, lane = tid & 63;
    const int row16 = lane & 15, kg = lane >> 4;
    const int bid = blockIdx.x;
    const int qtile = bid & 7, g = (bid >> 3) & 3, b = (bid >> 5) & 1, hkv = bid >> 6;
    const int hq = hkv * 4 + g;
    const int qbase = qtile * 256 + w * 32;

    ushort8 qf[2][4];
#pragma unroll
    for (int s = 0; s < 2; ++s) {
        const int qrow = qbase + s * 16 + row16;
        const float* qp = Q + (size_t)qrow * QSTRIDE + b * (NHQ * HD) + hq * HD;
#pragma unroll
        for (int kk = 0; kk < 4; ++kk) {
            const float* p = qp + kk * 32 + kg * 8;
            float4 f0 = *(const float4*)(p);
            float4 f1 = *(const float4*)(p + 4);
            ushort8 u;
            u[0] = f2bf(f0.x * SCALE); u[1] = f2bf(f0.y * SCALE);
            u[2] = f2bf(f0.z * SCALE); u[3] = f2bf(f0.w * SCALE);
            u[4] = f2bf(f1.x * SCALE); u[5] = f2bf(f1.y * SCALE);
            u[6] = f2bf(f1.z * SCALE); u[7] = f2bf(f1.w * SCALE);
            qf[s][kk] = u;
        }
    }
    float m[2][4], lsum[2][4];
    f32x4 acco[2][8];
#pragma unroll
    for (int s = 0; s < 2; ++s)
#pragma unroll
        for (int r = 0; r < 4; ++r) { m[s][r] = -1e30f; lsum[s][r] = 0.f; }
#pragma unroll
    for (int s = 0; s < 2; ++s)
#pragma unroll
        for (int n = 0; n < 8; ++n) acco[s][n] = (f32x4)0.f;

    const float* kb0 = K + b * (NHKV * HD) + hkv * HD;
    const float* vb0 = V + b * (NHKV * HD) + hkv * HD;

    for (int kvt = 0; kvt < SEQ / KVB; ++kvt) {
        const int kv0 = kvt * KVB;
        __syncthreads();
        const float* kb = kb0 + (size_t)kv0 * KSTRIDE;
#pragma unroll
        for (int i = 0; i < 2; ++i) {
            int c = i * 512 + tid;
            int row = c >> 4, c8 = c & 15;
            const float* src = kb + (size_t)row * KSTRIDE + c8 * 8;
            float4 f0 = *(const float4*)(src);
            float4 f1 = *(const float4*)(src + 4);
            ushort8 u;
            u[0] = f2bf(f0.x); u[1] = f2bf(f0.y); u[2] = f2bf(f0.z); u[3] = f2bf(f0.w);
            u[4] = f2bf(f1.x); u[5] = f2bf(f1.y); u[6] = f2bf(f1.z); u[7] = f2bf(f1.w);
            *(ushort8*)&kbuf[row * KPAD + c8 * 8] = u;
        }
        const float* vb = vb0 + (size_t)kv0 * KSTRIDE;
#pragma unroll
        for (int i = 0; i < 4; ++i) {
            int f4i = i * 512 + tid;
            int kv = f4i >> 5, d0 = (f4i & 31) * 4;
            float4 v4 = *(const float4*)(vb + (size_t)kv * KSTRIDE + d0);
            vbuf[(d0 + 0) * VPAD + kv] = f2bf(v4.x);
            vbuf[(d0 + 1) * VPAD + kv] = f2bf(v4.y);
            vbuf[(d0 + 2) * VPAD + kv] = f2bf(v4.z);
            vbuf[(d0 + 3) * VPAD + kv] = f2bf(v4.w);
        }
        __syncthreads();

        f32x4 sa[2][4];
#pragma unroll
        for (int s = 0; s < 2; ++s)
#pragma unroll
            for (int n = 0; n < 4; ++n) sa[s][n] = (f32x4)0.f;
#pragma unroll
        for (int kk = 0; kk < 4; ++kk) {
#pragma unroll
            for (int n = 0; n < 4; ++n) {
                bf16x8 bfr = *(const bf16x8*)&kbuf[(n * 16 + row16) * KPAD + kk * 32 + kg * 8];
                sa[0][n] = __builtin_amdgcn_mfma_f32_16x16x32_bf16(
                    __builtin_bit_cast(bf16x8, qf[0][kk]), bfr, sa[0][n], 0, 0, 0);
                sa[1][n] = __builtin_amdgcn_mfma_f32_16x16x32_bf16(
                    __builtin_bit_cast(bf16x8, qf[1][kk]), bfr, sa[1][n], 0, 0, 0);
            }
        }
#pragma unroll
        for (int s = 0; s < 2; ++s) {
#pragma unroll
            for (int r = 0; r < 4; ++r) {
                float tm = fmaxf(fmaxf(sa[s][0][r], sa[s][1][r]), fmaxf(sa[s][2][r], sa[s][3][r]));
                tm = fmaxf(tm, __shfl_xor(tm, 1, 16));
                tm = fmaxf(tm, __shfl_xor(tm, 2, 16));
                tm = fmaxf(tm, __shfl_xor(tm, 4, 16));
                tm = fmaxf(tm, __shfl_xor(tm, 8, 16));
                float mn = fmaxf(m[s][r], tm);
                float corr = __expf(m[s][r] - mn);
                float ps = 0.f;
                int prow = kg * 4 + r;
#pragma unroll
                for (int n = 0; n < 4; ++n) {
                    float p = __expf(sa[s][n][r] - mn);
                    ps += p;
                    pbuf[w][prow * PPAD + n * 16 + row16] = f2bf(p);
                }
                ps += __shfl_xor(ps, 1, 16);
                ps += __shfl_xor(ps, 2, 16);
                ps += __shfl_xor(ps, 4, 16);
                ps += __shfl_xor(ps, 8, 16);
                lsum[s][r] = lsum[s][r] * corr + ps;
                m[s][r] = mn;
#pragma unroll
                for (int n8 = 0; n8 < 8; ++n8) acco[s][n8][r] *= corr;
            }
#pragma unroll
            for (int kk2 = 0; kk2 < 2; ++kk2) {
                bf16x8 pa = *(const bf16x8*)&pbuf[w][row16 * PPAD + kk2 * 32 + kg * 8];
#pragma unroll
                for (int n8 = 0; n8 < 8; ++n8) {
                    bf16x8 vf = *(const bf16x8*)&vbuf[(n8 * 16 + row16) * VPAD + kk2 * 32 + kg * 8];
                    acco[s][n8] = __builtin_amdgcn_mfma_f32_16x16x32_bf16(pa, vf, acco[s][n8], 0, 0, 0);
                }
            }
        }
    }
    float* ob = O + b * (NHQ * HD) + hq * HD;
#pragma unroll
    for (int s = 0; s < 2; ++s)
#pragma unroll
        for (int r = 0; r < 4; ++r) {
            float inv = 1.f / lsum[s][r];
            int qrow = qbase + s * 16 + kg * 4 + r;
            float* op = ob + (size_t)qrow * QSTRIDE;
#pragma unroll
            for (int n8 = 0; n8 < 8; ++n8)
                op[n8 * 16 + row16] = acco[s][n8][r] * inv;
        }
}

extern "C" void kernel_launch(void* const* d_in, const int* in_sizes, int n_in,
                              void* d_out, int out_size, void* d_ws, size_t ws_size,
                              hipStream_t stream) {
    (void)in_sizes; (void)n_in; (void)out_size;
    const float* Q = (const float*)d_in[0];
    const float* K = (const float*)d_in[1];
    const float* V = (const float*)d_in[2];
    float* Out = (float*)d_out;

    const size_t kv_elems = (size_t)16 * 2048 * 128;
    const size_t need = kv_elems * 2 * sizeof(unsigned short);

    if (ws_size >= need) {
        unsigned short* Kws = (unsigned short*)d_ws;
        unsigned short* Vt  = Kws + kv_elems;
        conv_k<<<dim3(2048), dim3(256), 0, stream>>>(K, Kws);
        conv_v<<<dim3(512), dim3(256), 0, stream>>>(V, Vt);
        attn_fwd6<<<dim3(512), dim3(512), 0, stream>>>(Q, Kws, Vt, Out);
    } else {
        attn_fwd<<<dim3(512), dim3(512), 0, stream>>>(Q, K, V, Out);
    }
}